// Round 4
// baseline (643.616 us; speedup 1.0000x reference)
//
#include <hip/hip_runtime.h>
#include <hip/hip_bf16.h>

#define NPTS 131072
// transposed feature region offsets (elements, fp32) in ws feature area:
//   scale0: 56*56*64 = 200704, scale1: 28*28*128 = 100352,
//   scale2: 14*14*256 = 50176, scale3: 7*7*512 = 25088  -> total 376320
#define FT_TOTAL 376320

// native clang vector type — required by __builtin_nontemporal_store
typedef float f32x4 __attribute__((ext_vector_type(4)));

// ------------------------------------------------------------------
// Kernel 1: per-point projection -> per-scale packed spatial index.
// Stores x1*S + y1, or -1 when the degenerate bilinear weight is 0.
// Numerics: __fdiv_rn/__fmul_rn/__fadd_rn match numpy f32 op-by-op
// (verified: absmax == 0.0 in round 2).
// ------------------------------------------------------------------
__global__ __launch_bounds__(256) void k_indices(
    const float* __restrict__ pts,
    int4* __restrict__ idx4)
{
    int n = blockIdx.x * 256 + threadIdx.x;
    if (n >= NPTS) return;
    float px = pts[3 * n + 0];
    float py = pts[3 * n + 1];
    float pz = pts[3 * n + 2];
    float qh = __fdiv_rn(py, pz);
    float qw = __fdiv_rn(px, -pz);
    float h = __fadd_rn(__fmul_rn(248.0f, qh), 111.5f);
    float w = __fadd_rn(__fmul_rn(248.0f, qw), 111.5f);
    h = fminf(fmaxf(h, 0.0f), 223.0f);
    w = fminf(fmaxf(w, 0.0f), 223.0f);

    const float scl[4] = {0.25f, 0.125f, 0.0625f, 0.03125f}; // S/224, exact pow2
    const int   S[4]   = {56, 28, 14, 7};
    int r[4];
#pragma unroll
    for (int s = 0; s < 4; ++s) {
        float x = h * scl[s];   // exact pow2 scaling
        float y = w * scl[s];
        int x1 = (int)floorf(x);
        int x2 = min((int)ceilf(x), S[s] - 1);
        int y1 = (int)floorf(y);
        int y2 = min((int)ceilf(y), S[s] - 1);
        int bit = (x2 - x1) * (y2 - y1);   // 0 or 1 (trunc==floor for x>=0)
        r[s] = bit ? (x1 * S[s] + y1) : -1;
    }
    idx4[n] = make_int4(r[0], r[1], r[2], r[3]);
}

// ------------------------------------------------------------------
// Kernel 2: transpose feat[b] slices [C,H,W] -> [H*W, C] (fp32) so the
// per-point channel gather becomes contiguous (float4-vectorizable).
// Only 1.5 MB total — latency-trivial.
// ------------------------------------------------------------------
__global__ __launch_bounds__(256) void k_transpose(
    const float* __restrict__ f0,
    const float* __restrict__ f1,
    const float* __restrict__ f2,
    const float* __restrict__ f3,
    const int* __restrict__ batch,
    float* __restrict__ ft)
{
    int d = blockIdx.x * 256 + threadIdx.x;
    if (d >= FT_TOTAL) return;
    int b = *batch;
    const float* src;
    int local, c, p, hw;
    if (d < 200704) {
        local = d;          c = local & 63;  p = local >> 6; hw = 3136;
        src = f0 + (size_t)b * 64 * 3136;
    } else if (d < 301056) {
        local = d - 200704; c = local & 127; p = local >> 7; hw = 784;
        src = f1 + (size_t)b * 128 * 784;
    } else if (d < 351232) {
        local = d - 301056; c = local & 255; p = local >> 8; hw = 196;
        src = f2 + (size_t)b * 256 * 196;
    } else {
        local = d - 351232; c = local & 511; p = local >> 9; hw = 49;
        src = f3 + (size_t)b * 512 * 49;
    }
    ft[d] = src[c * hw + p];
}

// ------------------------------------------------------------------
// Kernel 3: the writer. One thread = 8 output channels (2 float4s,
// 32 B contiguous per lane). 120 threads per point. Output stores are
// NON-TEMPORAL so the 504 MB store stream does not thrash L2 and evict
// the 1.5 MB transposed-feature working set the loads depend on.
// ------------------------------------------------------------------
__global__ __launch_bounds__(256) void k_gather(
    const int* __restrict__ idx,     // [N][4]
    const float* __restrict__ ft,    // transposed feats (L2-resident)
    float* __restrict__ out)         // [N, 960]
{
    int t = blockIdx.x * 256 + threadIdx.x;   // total = N*120 exactly
    int n = t / 120;                          // const div -> magic mul
    int j2 = t - n * 120;
    int j = j2 * 2;                           // float4-chunk index (0..238)

    // scale boundaries at j = 16, 48, 112 are all even -> a (j, j+1) pair
    // never straddles scales.
    int s, C, toff, cb;
    if (j < 16)       { s = 0; C = 64;  toff = 0;      cb = j * 4; }
    else if (j < 48)  { s = 1; C = 128; toff = 200704; cb = (j - 16) * 4; }
    else if (j < 112) { s = 2; C = 256; toff = 301056; cb = (j - 48) * 4; }
    else              { s = 3; C = 512; toff = 351232; cb = (j - 112) * 4; }

    int id = idx[n * 4 + s];
    f32x4 v0 = (f32x4)(0.0f);
    f32x4 v1 = (f32x4)(0.0f);
    if (id >= 0) {
        const f32x4* src = (const f32x4*)(ft + toff + id * C + cb);
        v0 = src[0];
        v1 = src[1];
    }
    f32x4* dst = (f32x4*)(out + (size_t)n * 960 + j * 4);  // 16B aligned
    __builtin_nontemporal_store(v0, dst);
    __builtin_nontemporal_store(v1, dst + 1);
}

extern "C" void kernel_launch(void* const* d_in, const int* in_sizes, int n_in,
                              void* d_out, int out_size, void* d_ws, size_t ws_size,
                              hipStream_t stream) {
    const float* f0  = (const float*)d_in[0];
    const float* f1  = (const float*)d_in[1];
    const float* f2  = (const float*)d_in[2];
    const float* f3  = (const float*)d_in[3];
    const float* pts = (const float*)d_in[4];
    const int* batch = (const int*)d_in[5];

    // ws layout: [ int4 idx[NPTS] : 2 MiB ][ f32 ft[FT_TOTAL] : 1.44 MiB ]
    int4* idx4 = (int4*)d_ws;
    float* ft = (float*)((char*)d_ws + (size_t)NPTS * 16);
    float* out = (float*)d_out;

    k_indices<<<NPTS / 256, 256, 0, stream>>>(pts, idx4);
    k_transpose<<<(FT_TOTAL + 255) / 256, 256, 0, stream>>>(f0, f1, f2, f3, batch, ft);
    // N*120 / 256 = 61440 blocks exactly
    k_gather<<<61440, 256, 0, stream>>>((const int*)idx4, ft, out);
}

// Round 5
// 485.232 us; speedup vs baseline: 1.3264x; 1.3264x over previous
//
#include <hip/hip_runtime.h>
#include <hip/hip_bf16.h>

#define NPTS 131072
// transposed feature region offsets (elements, fp32) in ws feature area:
//   scale0: 56*56*64 = 200704, scale1: 28*28*128 = 100352,
//   scale2: 14*14*256 = 50176, scale3: 7*7*512 = 25088  -> total 376320
#define FT_TOTAL 376320

// native clang vector type — required by __builtin_nontemporal_store
typedef float f32x4 __attribute__((ext_vector_type(4)));

// ------------------------------------------------------------------
// Kernel 1: per-point projection -> per-scale packed spatial index.
// Stores x1*S + y1, or -1 when the degenerate bilinear weight is 0.
// Numerics: __fdiv_rn/__fmul_rn/__fadd_rn match numpy f32 op-by-op
// (verified: absmax == 0.0 in rounds 2 and 4).
// ------------------------------------------------------------------
__global__ __launch_bounds__(256) void k_indices(
    const float* __restrict__ pts,
    int4* __restrict__ idx4)
{
    int n = blockIdx.x * 256 + threadIdx.x;
    if (n >= NPTS) return;
    float px = pts[3 * n + 0];
    float py = pts[3 * n + 1];
    float pz = pts[3 * n + 2];
    float qh = __fdiv_rn(py, pz);
    float qw = __fdiv_rn(px, -pz);
    float h = __fadd_rn(__fmul_rn(248.0f, qh), 111.5f);
    float w = __fadd_rn(__fmul_rn(248.0f, qw), 111.5f);
    h = fminf(fmaxf(h, 0.0f), 223.0f);
    w = fminf(fmaxf(w, 0.0f), 223.0f);

    const float scl[4] = {0.25f, 0.125f, 0.0625f, 0.03125f}; // S/224, exact pow2
    const int   S[4]   = {56, 28, 14, 7};
    int r[4];
#pragma unroll
    for (int s = 0; s < 4; ++s) {
        float x = h * scl[s];   // exact pow2 scaling
        float y = w * scl[s];
        int x1 = (int)floorf(x);
        int x2 = min((int)ceilf(x), S[s] - 1);
        int y1 = (int)floorf(y);
        int y2 = min((int)ceilf(y), S[s] - 1);
        int bit = (x2 - x1) * (y2 - y1);   // 0 or 1 (trunc==floor for x>=0)
        r[s] = bit ? (x1 * S[s] + y1) : -1;
    }
    idx4[n] = make_int4(r[0], r[1], r[2], r[3]);
}

// ------------------------------------------------------------------
// Kernel 2: transpose feat[b] slices [C,H,W] -> [H*W, C] (fp32) so the
// per-point channel gather becomes contiguous (float4-vectorizable).
// Only 1.5 MB total — latency-trivial.
// ------------------------------------------------------------------
__global__ __launch_bounds__(256) void k_transpose(
    const float* __restrict__ f0,
    const float* __restrict__ f1,
    const float* __restrict__ f2,
    const float* __restrict__ f3,
    const int* __restrict__ batch,
    float* __restrict__ ft)
{
    int d = blockIdx.x * 256 + threadIdx.x;
    if (d >= FT_TOTAL) return;
    int b = *batch;
    const float* src;
    int local, c, p, hw;
    if (d < 200704) {
        local = d;          c = local & 63;  p = local >> 6; hw = 3136;
        src = f0 + (size_t)b * 64 * 3136;
    } else if (d < 301056) {
        local = d - 200704; c = local & 127; p = local >> 7; hw = 784;
        src = f1 + (size_t)b * 128 * 784;
    } else if (d < 351232) {
        local = d - 301056; c = local & 255; p = local >> 8; hw = 196;
        src = f2 + (size_t)b * 256 * 196;
    } else {
        local = d - 351232; c = local & 511; p = local >> 9; hw = 49;
        src = f3 + (size_t)b * 512 * 49;
    }
    ft[d] = src[c * hw + p];
}

// ------------------------------------------------------------------
// Kernel 3: the writer. One thread = 4 output channels (one float4).
// 240 float4 per point; consecutive lanes write consecutive 16 B ->
// each store instruction covers a fully-populated contiguous 1 KiB.
// Non-temporal: keep the 504 MB store stream out of L2 so the 1.5 MB
// transposed-feature working set stays resident.
// ------------------------------------------------------------------
__global__ __launch_bounds__(256) void k_gather(
    const int* __restrict__ idx,     // [N][4]
    const float* __restrict__ ft,    // transposed feats (L2-resident)
    float* __restrict__ out)         // [N, 960]
{
    int gid = blockIdx.x * 256 + threadIdx.x;  // total = N*240 exactly
    int n = gid / 240;                          // const div -> magic mul
    int j = gid - n * 240;                      // float4 chunk within row

    int s, C, toff, cb;
    if (j < 16)       { s = 0; C = 64;  toff = 0;      cb = j * 4; }
    else if (j < 48)  { s = 1; C = 128; toff = 200704; cb = (j - 16) * 4; }
    else if (j < 112) { s = 2; C = 256; toff = 301056; cb = (j - 48) * 4; }
    else              { s = 3; C = 512; toff = 351232; cb = (j - 112) * 4; }

    int id = idx[n * 4 + s];
    f32x4 v = (f32x4)(0.0f);
    if (id >= 0) {
        v = *(const f32x4*)(ft + toff + id * C + cb);  // coalesced L2 hit
    }
    f32x4* dst = (f32x4*)(out + (size_t)n * 960 + j * 4);  // 16B aligned
    __builtin_nontemporal_store(v, dst);
}

extern "C" void kernel_launch(void* const* d_in, const int* in_sizes, int n_in,
                              void* d_out, int out_size, void* d_ws, size_t ws_size,
                              hipStream_t stream) {
    const float* f0  = (const float*)d_in[0];
    const float* f1  = (const float*)d_in[1];
    const float* f2  = (const float*)d_in[2];
    const float* f3  = (const float*)d_in[3];
    const float* pts = (const float*)d_in[4];
    const int* batch = (const int*)d_in[5];

    // ws layout: [ int4 idx[NPTS] : 2 MiB ][ f32 ft[FT_TOTAL] : 1.44 MiB ]
    int4* idx4 = (int4*)d_ws;
    float* ft = (float*)((char*)d_ws + (size_t)NPTS * 16);
    float* out = (float*)d_out;

    k_indices<<<NPTS / 256, 256, 0, stream>>>(pts, idx4);
    k_transpose<<<(FT_TOTAL + 255) / 256, 256, 0, stream>>>(f0, f1, f2, f3, batch, ft);
    // N*240 / 256 = 122880 blocks exactly
    k_gather<<<122880, 256, 0, stream>>>((const int*)idx4, ft, out);
}